// Round 1
// baseline (993.203 us; speedup 1.0000x reference)
//
#include <hip/hip_runtime.h>

// RecursiveNN: 11-level binary tree, shared linear map W(128x256)+b, bf16 MFMA.
// Fused 2-kernel pipeline:
//   pack_w: W -> per-lane MFMA B-fragment order (bf16) + zero per-batch counters.
//   tree:   one block = 128 contiguous leaves; fp32 gather + packed cvt -> LDS;
//           7 fused level-steps (128->2); then per-batch atomic election: the
//           16th (last) group of a batch runs the final 5 levels (32->1) in-block.
// LDS = exactly 40960 B (bufA 128 rows + bufB 32 rows, unpadded 256 B rows with
// XOR swizzle) -> 4 blocks/CU on the 160 KiB pool (was 3 at 43520 B padded).

typedef __bf16 bf16x8 __attribute__((ext_vector_type(8)));
typedef __bf16 bf16x4 __attribute__((ext_vector_type(4)));
typedef float f32x4 __attribute__((ext_vector_type(4)));

// Swizzled LDS element index: rows of 128 bf16 (256 B, no pad).
//   idx = row*128 + (col ^ (((row>>1)&7) << 3))
// MFMA A-frag read: 16 lanes at rows 2*lm+hi, same col -> XOR spreads across 8
// distinct 16B slots -> uniform 8 accesses/bank = ds_read_b128 minimum (no
// conflict cycles). Row offsets used between buffers are multiples of 32 rows,
// so relative-row addressing keeps the swizzle consistent.
__device__ __forceinline__ int lidx(int row, int col) {
    return (row << 7) + (col ^ ((row & 14) << 2));
}

// Pack W (fp32 128x256) into MFMA B-fragment lane order (bf16):
//   frag f=nl*8+kk, wave wv, lane l: elem j = W[o][d+j],
//   o=(2wv+nl)*16+(l&15), d=kk*32+(l>>4)*8; stored at wpack[(f*256+tid)*8].
// Block 0 also zeroes the 256 per-batch election counters.
__global__ void pack_w_kernel(const float* __restrict__ W,
                              __bf16* __restrict__ wpack,
                              unsigned int* __restrict__ cnt) {
    const int f = blockIdx.x;
    const int tid = threadIdx.x;
    if (f == 0) cnt[tid] = 0u;
    const int wv = tid >> 6, l = tid & 63;
    const int nl = f >> 3, kk = f & 7;
    const int o = ((wv << 1) + nl) * 16 + (l & 15);
    const int d = kk * 32 + ((l >> 4) << 3);
    const float* src = W + o * 256 + d;
    bf16x8 h;
#pragma unroll
    for (int j = 0; j < 8; ++j) h[j] = (__bf16)src[j];
    *(bf16x8*)(wpack + (size_t)(f * 256 + tid) * 8) = h;
}

// One level-step: NOUT local outputs from 2*NOUT local input rows.
// src0 = rows 0..31, src1 = rows 32..63 (unused when NOUT<=16). Ends in barrier.
template <int NOUT>
__device__ __forceinline__ void level_step(
    const __bf16* src0, const __bf16* src1, __bf16* dst,
    const bf16x8* wf, const float* bval, int wv, int q, int lm)
{
    const int ntm = (NOUT + 15) >> 4;
#pragma unroll
    for (int mt = 0; mt < ntm; ++mt) {
        const __bf16* src = mt ? src1 : src0;
        // clamp: padded lanes broadcast row 0/1 (free; no garbage traffic)
        const int me = (NOUT >= 16) ? lm : (lm < NOUT ? lm : 0);
        bf16x8 af[8];
#pragma unroll
        for (int kk = 0; kk < 8; ++kk) {
            const int hi = kk >> 2;                   // k >= 128 half
            const int col = (kk & 3) * 32 + q * 8;
            const int row = 2 * me + hi;              // local row 0..31
            af[kk] = *(const bf16x8*)&src[lidx(row, col)];
        }
#pragma unroll
        for (int nl = 0; nl < 2; ++nl) {
            f32x4 acc = { bval[nl], bval[nl], bval[nl], bval[nl] };
#pragma unroll
            for (int kk = 0; kk < 8; ++kk)
                acc = __builtin_amdgcn_mfma_f32_16x16x32_bf16(
                    af[kk], wf[nl * 8 + kk], acc, 0, 0, 0);
            const int col = (2 * wv + nl) * 16 + lm;  // D col = lane&15
            const bf16x4 hv = __builtin_convertvector(acc, bf16x4);
#pragma unroll
            for (int r = 0; r < 4; ++r) {
                const int row = mt * 16 + q * 4 + r;  // D row
                if (row < NOUT)
                    dst[lidx(row, col)] = hv[r];
            }
        }
    }
    __syncthreads();
}

// 4 input rows -> 2 subtree roots straight to global (bf16). No barrier.
__device__ __forceinline__ void level_final(
    const __bf16* src, __bf16* yrow,
    const bf16x8* wf, const float* bval, int wv, int q, int lm)
{
    const int me = (lm < 2) ? lm : 0;
    bf16x8 af[8];
#pragma unroll
    for (int kk = 0; kk < 8; ++kk) {
        const int hi = kk >> 2;
        const int col = (kk & 3) * 32 + q * 8;
        af[kk] = *(const bf16x8*)&src[lidx(2 * me + hi, col)];
    }
#pragma unroll
    for (int nl = 0; nl < 2; ++nl) {
        f32x4 acc = { bval[nl], bval[nl], bval[nl], bval[nl] };
#pragma unroll
        for (int kk = 0; kk < 8; ++kk)
            acc = __builtin_amdgcn_mfma_f32_16x16x32_bf16(
                af[kk], wf[nl * 8 + kk], acc, 0, 0, 0);
        const int col = (2 * wv + nl) * 16 + lm;
        if (q == 0) {                 // rows 0,1 = quad 0 regs 0,1
            yrow[0 * 128 + col] = (__bf16)acc[0];
            yrow[1 * 128 + col] = (__bf16)acc[1];
        }
    }
}

// Fused kernel: one block = 128 contiguous leaves of one batch.
// Scratch rotation (abs rows):
//   L1a: A[0:63]  -> B[0:31]    L1b: A[64:127]-> A[0:31]
//   L2:  B+A[0:31]-> A[32:63]   L3:  A[32:63] -> B[0:15]
//   L4:  B[0:15]  -> A[0:7]     L5:  A[0:7]   -> B[0:3]
//   L6:  B[0:3]   -> y (2 rows, bf16)
// Then: __threadfence + per-batch atomicAdd; the block seeing old==15 reloads
// the batch's 32 roots from y and runs the final 5 levels -> fp32 out row.
__global__ __launch_bounds__(256, 4) void tree_kernel(
    const int* __restrict__ wid, const float* __restrict__ emb,
    const __bf16* __restrict__ wpack, const float* __restrict__ bias,
    __bf16* __restrict__ y, unsigned int* __restrict__ cnt,
    float* __restrict__ out)
{
    __shared__ __align__(16) __bf16 bufA[128 * 128];  // 32 KB
    __shared__ __align__(16) __bf16 bufB[32 * 128];   // 8 KB -> 40960 B total
    const int tid = threadIdx.x;
    const int batch = blockIdx.x >> 4;   // 16 groups of 128 leaves per batch
    const int grp = blockIdx.x & 15;
    const int wv = tid >> 6, ln = tid & 63, q = ln >> 4, lm = ln & 15;

    // Leaf ids first: they head the gather's dependent chain (wf/bias loads
    // fill the latency shadow).
    const int* wb = wid + batch * 2048 + grp * 128;
    int idreg[16];
#pragma unroll
    for (int i = 0; i < 16; ++i) idreg[i] = wb[(tid >> 5) + 8 * i];

    // W fragments: 16 x (8 bf16) = 64 VGPRs, coalesced 256B per thread.
    bf16x8 wf[16];
    const bf16x8* wp = (const bf16x8*)wpack;
#pragma unroll
    for (int f = 0; f < 16; ++f) wf[f] = wp[f * 256 + tid];
    float bval[2];
    bval[0] = bias[(2 * wv + 0) * 16 + lm];
    bval[1] = bias[(2 * wv + 1) * 16 + lm];

    // Gather 128 rows x 128 fp32 -> bf16 LDS (coalesced 512B per row-group).
#pragma unroll
    for (int i = 0; i < 16; ++i) {
        const int row = (tid >> 5) + 8 * i;
        const int c4 = tid & 31;
        const f32x4 v = *(const f32x4*)(emb + (size_t)idreg[i] * 128 + c4 * 4);
        *(bf16x4*)&bufA[lidx(row, c4 * 4)] =
            __builtin_convertvector(v, bf16x4);
    }
    __syncthreads();

    level_step<32>(bufA,            bufA + 32 * 128, bufB,            wf, bval, wv, q, lm);
    level_step<32>(bufA + 64 * 128, bufA + 96 * 128, bufA,            wf, bval, wv, q, lm);
    level_step<32>(bufB,            bufA,            bufA + 32 * 128, wf, bval, wv, q, lm);
    level_step<16>(bufA + 32 * 128, nullptr,         bufB,            wf, bval, wv, q, lm);
    level_step<8> (bufB,            nullptr,         bufA,            wf, bval, wv, q, lm);
    level_step<4> (bufA,            nullptr,         bufB,            wf, bval, wv, q, lm);
    level_final(bufB, y + (size_t)(batch * 32 + grp * 2) * 128,
                wf, bval, wv, q, lm);

    // Publish roots + elect the last group of this batch.
    __threadfence();          // make this thread's y stores device-visible
    __syncthreads();          // order all block threads' stores before the atomic
    int* flagp = (int*)bufB;  // bufB dead after level_final + barrier
    if (tid == 0) {
        const unsigned int old = __hip_atomic_fetch_add(
            &cnt[batch], 1u, __ATOMIC_ACQ_REL, __HIP_MEMORY_SCOPE_AGENT);
        flagp[0] = (old == 15u);
    }
    __syncthreads();
    if (!flagp[0]) return;

    // ---- winner tail: 32 subtree roots -> 5 levels -> fp32 output row ----
#pragma unroll
    for (int i = 0; i < 2; ++i) {
        const int flat = tid + 256 * i;
        const int row = flat >> 4;
        const int c8 = flat & 15;
        const bf16x8 v =
            *(const bf16x8*)(y + (size_t)(batch * 32 + row) * 128 + c8 * 8);
        *(bf16x8*)&bufA[lidx(row, c8 * 8)] = v;
    }
    __syncthreads();
    level_step<16>(bufA, nullptr, bufB, wf, bval, wv, q, lm);
    level_step<8> (bufB, nullptr, bufA, wf, bval, wv, q, lm);
    level_step<4> (bufA, nullptr, bufB, wf, bval, wv, q, lm);
    level_step<2> (bufB, nullptr, bufA, wf, bval, wv, q, lm);

    // 2 rows in bufA -> root (fp32 out).
    {
        bf16x8 af[8];
#pragma unroll
        for (int kk = 0; kk < 8; ++kk) {
            const int hi = kk >> 2;
            const int col = (kk & 3) * 32 + q * 8;
            af[kk] = *(const bf16x8*)&bufA[lidx(hi, col)];
        }
#pragma unroll
        for (int nl = 0; nl < 2; ++nl) {
            f32x4 acc = { bval[nl], bval[nl], bval[nl], bval[nl] };
#pragma unroll
            for (int kk = 0; kk < 8; ++kk)
                acc = __builtin_amdgcn_mfma_f32_16x16x32_bf16(
                    af[kk], wf[nl * 8 + kk], acc, 0, 0, 0);
            const int col = (2 * wv + nl) * 16 + lm;
            if (q == 0) out[(size_t)batch * 128 + col] = acc[0];
        }
    }
}

extern "C" void kernel_launch(void* const* d_in, const int* in_sizes, int n_in,
                              void* d_out, int out_size, void* d_ws, size_t ws_size,
                              hipStream_t stream) {
    const int*   wid = (const int*)d_in[0];      // (256, 2048) int32
    const float* emb = (const float*)d_in[1];    // (100000, 128) fp32
    const float* W   = (const float*)d_in[2];    // (128, 256) fp32
    const float* b   = (const float*)d_in[3];    // (128,) fp32
    float* out = (float*)d_out;                  // (256, 128) fp32

    __bf16* wpack = (__bf16*)d_ws;               // 32768 elems = 64 KB
    __bf16* y     = wpack + 32768;               // (256,32,128) bf16 = 2 MB
    unsigned int* cnt = (unsigned int*)(y + 256 * 32 * 128);  // 256 x u32 = 1 KB

    pack_w_kernel<<<16, 256, 0, stream>>>(W, wpack, cnt);
    tree_kernel<<<4096, 256, 0, stream>>>(wid, emb, wpack, b, y, cnt, out);
}

// Round 2
// 682.087 us; speedup vs baseline: 1.4561x; 1.4561x over previous
//
#include <hip/hip_runtime.h>

// RecursiveNN: 11-level binary tree, shared linear map W(128x256)+b, bf16 MFMA.
// Fused 2-kernel pipeline:
//   pack_w: W -> per-lane MFMA B-fragment order (bf16) + zero per-batch counters.
//   tree:   one block = 128 contiguous leaves; fp32 gather + packed cvt -> LDS;
//           7 fused level-steps (128->2); then per-batch atomic election: the
//           16th (last) group of a batch runs the final 5 levels (32->1) in-block.
// LDS layout: STRIDE=136 padded rows (272 B) -> row rotates banks by 4; measured
// 0 conflicts. 43520 B total -> 3 blocks/CU. launch_bounds(256,3): proven no-spill
// codegen (72 VGPR + 64 AGPR for wf). (256,4) forces a 128-reg budget -> scratch
// spill, +630 MB HBM traffic, 19x regression (round-1 post-mortem).

typedef __bf16 bf16x8 __attribute__((ext_vector_type(8)));
typedef __bf16 bf16x4 __attribute__((ext_vector_type(4)));
typedef float f32x4 __attribute__((ext_vector_type(4)));

#define STRIDE 136  // 128 cols + 8 pad bf16 = 272B rows; 0 LDS conflicts measured

// Pack W (fp32 128x256) into MFMA B-fragment lane order (bf16):
//   frag f=nl*8+kk, wave wv, lane l: elem j = W[o][d+j],
//   o=(2wv+nl)*16+(l&15), d=kk*32+(l>>4)*8; stored at wpack[(f*256+tid)*8].
// Block 0 also zeroes the 256 per-batch election counters.
__global__ void pack_w_kernel(const float* __restrict__ W,
                              __bf16* __restrict__ wpack,
                              unsigned int* __restrict__ cnt) {
    const int f = blockIdx.x;
    const int tid = threadIdx.x;
    if (f == 0) cnt[tid] = 0u;
    const int wv = tid >> 6, l = tid & 63;
    const int nl = f >> 3, kk = f & 7;
    const int o = ((wv << 1) + nl) * 16 + (l & 15);
    const int d = kk * 32 + ((l >> 4) << 3);
    const float* src = W + o * 256 + d;
    bf16x8 h;
#pragma unroll
    for (int j = 0; j < 8; ++j) h[j] = (__bf16)src[j];
    *(bf16x8*)(wpack + (size_t)(f * 256 + tid) * 8) = h;
}

// One level-step: NOUT local outputs from 2*NOUT local input rows.
// src0 = rows 0..31, src1 = rows 32..63 (unused when NOUT<=16). Ends in barrier.
template <int NOUT>
__device__ __forceinline__ void level_step(
    const __bf16* src0, const __bf16* src1, __bf16* dst,
    const bf16x8* wf, const float* bval, int wv, int q, int lm)
{
    const int ntm = (NOUT + 15) >> 4;
#pragma unroll
    for (int mt = 0; mt < ntm; ++mt) {
        const __bf16* src = mt ? src1 : src0;
        // clamp: padded lanes broadcast row 0/1 (free; no garbage traffic)
        const int me = (NOUT >= 16) ? lm : (lm < NOUT ? lm : 0);
        bf16x8 af[8];
#pragma unroll
        for (int kk = 0; kk < 8; ++kk) {
            const int hi = kk >> 2;                   // k >= 128 half
            const int col = (kk & 3) * 32 + q * 8;
            const int row = 2 * me + hi;              // local row 0..31
            af[kk] = *(const bf16x8*)&src[row * STRIDE + col];
        }
#pragma unroll
        for (int nl = 0; nl < 2; ++nl) {
            f32x4 acc = { bval[nl], bval[nl], bval[nl], bval[nl] };
#pragma unroll
            for (int kk = 0; kk < 8; ++kk)
                acc = __builtin_amdgcn_mfma_f32_16x16x32_bf16(
                    af[kk], wf[nl * 8 + kk], acc, 0, 0, 0);
            const int col = (2 * wv + nl) * 16 + lm;  // D col = lane&15
            const bf16x4 hv = __builtin_convertvector(acc, bf16x4);
#pragma unroll
            for (int r = 0; r < 4; ++r) {
                const int row = mt * 16 + q * 4 + r;  // D row
                if (row < NOUT)
                    dst[row * STRIDE + col] = hv[r];
            }
        }
    }
    __syncthreads();
}

// 4 input rows -> 2 subtree roots straight to global (bf16). No barrier.
__device__ __forceinline__ void level_final(
    const __bf16* src, __bf16* yrow,
    const bf16x8* wf, const float* bval, int wv, int q, int lm)
{
    const int me = (lm < 2) ? lm : 0;
    bf16x8 af[8];
#pragma unroll
    for (int kk = 0; kk < 8; ++kk) {
        const int hi = kk >> 2;
        const int col = (kk & 3) * 32 + q * 8;
        af[kk] = *(const bf16x8*)&src[(2 * me + hi) * STRIDE + col];
    }
#pragma unroll
    for (int nl = 0; nl < 2; ++nl) {
        f32x4 acc = { bval[nl], bval[nl], bval[nl], bval[nl] };
#pragma unroll
        for (int kk = 0; kk < 8; ++kk)
            acc = __builtin_amdgcn_mfma_f32_16x16x32_bf16(
                af[kk], wf[nl * 8 + kk], acc, 0, 0, 0);
        const int col = (2 * wv + nl) * 16 + lm;
        if (q == 0) {                 // rows 0,1 = quad 0 regs 0,1
            yrow[0 * 128 + col] = (__bf16)acc[0];
            yrow[1 * 128 + col] = (__bf16)acc[1];
        }
    }
}

// Fused kernel: one block = 128 contiguous leaves of one batch.
// Scratch rotation (abs rows):
//   L1a: A[0:63]  -> B[0:31]    L1b: A[64:127]-> A[0:31]
//   L2:  B+A[0:31]-> A[32:63]   L3:  A[32:63] -> B[0:15]
//   L4:  B[0:15]  -> A[0:7]     L5:  A[0:7]   -> B[0:3]
//   L6:  B[0:3]   -> y (2 rows, bf16)
// Then: __threadfence + per-batch atomicAdd; the block seeing old==15 reloads
// the batch's 32 roots from y and runs the final 5 levels -> fp32 out row.
__global__ __launch_bounds__(256, 3) void tree_kernel(
    const int* __restrict__ wid, const float* __restrict__ emb,
    const __bf16* __restrict__ wpack, const float* __restrict__ bias,
    __bf16* __restrict__ y, unsigned int* __restrict__ cnt,
    float* __restrict__ out)
{
    __shared__ __align__(16) __bf16 bufA[128 * STRIDE];  // 34 KB
    __shared__ __align__(16) __bf16 bufB[32 * STRIDE];   // 8.5 KB -> 43.5 total
    const int tid = threadIdx.x;
    const int batch = blockIdx.x >> 4;   // 16 groups of 128 leaves per batch
    const int grp = blockIdx.x & 15;
    const int wv = tid >> 6, ln = tid & 63, q = ln >> 4, lm = ln & 15;

    // Leaf ids first: they head the gather's dependent chain (wf/bias loads
    // fill the latency shadow).
    const int* wb = wid + batch * 2048 + grp * 128;
    int idreg[16];
#pragma unroll
    for (int i = 0; i < 16; ++i) idreg[i] = wb[(tid >> 5) + 8 * i];

    // W fragments: 16 x (8 bf16) = 64 regs (AGPR-resident), coalesced 256B/thread.
    bf16x8 wf[16];
    const bf16x8* wp = (const bf16x8*)wpack;
#pragma unroll
    for (int f = 0; f < 16; ++f) wf[f] = wp[f * 256 + tid];
    float bval[2];
    bval[0] = bias[(2 * wv + 0) * 16 + lm];
    bval[1] = bias[(2 * wv + 1) * 16 + lm];

    // Gather 128 rows x 128 fp32 -> bf16 LDS (coalesced 512B per row-group).
#pragma unroll
    for (int i = 0; i < 16; ++i) {
        const int row = (tid >> 5) + 8 * i;
        const int c4 = tid & 31;
        const f32x4 v = *(const f32x4*)(emb + (size_t)idreg[i] * 128 + c4 * 4);
        *(bf16x4*)&bufA[row * STRIDE + c4 * 4] =
            __builtin_convertvector(v, bf16x4);
    }
    __syncthreads();

    level_step<32>(bufA,               bufA + 32 * STRIDE, bufB,               wf, bval, wv, q, lm);
    level_step<32>(bufA + 64 * STRIDE, bufA + 96 * STRIDE, bufA,               wf, bval, wv, q, lm);
    level_step<32>(bufB,               bufA,               bufA + 32 * STRIDE, wf, bval, wv, q, lm);
    level_step<16>(bufA + 32 * STRIDE, nullptr,            bufB,               wf, bval, wv, q, lm);
    level_step<8> (bufB,               nullptr,            bufA,               wf, bval, wv, q, lm);
    level_step<4> (bufA,               nullptr,            bufB,               wf, bval, wv, q, lm);
    level_final(bufB, y + (size_t)(batch * 32 + grp * 2) * 128,
                wf, bval, wv, q, lm);

    // Publish roots + elect the last group of this batch.
    __threadfence();          // make this thread's y stores device-visible
    __syncthreads();          // order all block threads' stores before the atomic
    int* flagp = (int*)bufB;  // bufB dead after level_final + barrier
    if (tid == 0) {
        const unsigned int old = __hip_atomic_fetch_add(
            &cnt[batch], 1u, __ATOMIC_ACQ_REL, __HIP_MEMORY_SCOPE_AGENT);
        flagp[0] = (old == 15u);
    }
    __syncthreads();
    if (!flagp[0]) return;

    // ---- winner tail: 32 subtree roots -> 5 levels -> fp32 output row ----
#pragma unroll
    for (int i = 0; i < 2; ++i) {
        const int flat = tid + 256 * i;
        const int row = flat >> 4;
        const int c8 = flat & 15;
        const bf16x8 v =
            *(const bf16x8*)(y + (size_t)(batch * 32 + row) * 128 + c8 * 8);
        *(bf16x8*)&bufA[row * STRIDE + c8 * 8] = v;
    }
    __syncthreads();
    level_step<16>(bufA, nullptr, bufB, wf, bval, wv, q, lm);
    level_step<8> (bufB, nullptr, bufA, wf, bval, wv, q, lm);
    level_step<4> (bufA, nullptr, bufB, wf, bval, wv, q, lm);
    level_step<2> (bufB, nullptr, bufA, wf, bval, wv, q, lm);

    // 2 rows in bufA -> root (fp32 out).
    {
        bf16x8 af[8];
#pragma unroll
        for (int kk = 0; kk < 8; ++kk) {
            const int hi = kk >> 2;
            const int col = (kk & 3) * 32 + q * 8;
            af[kk] = *(const bf16x8*)&bufA[hi * STRIDE + col];
        }
#pragma unroll
        for (int nl = 0; nl < 2; ++nl) {
            f32x4 acc = { bval[nl], bval[nl], bval[nl], bval[nl] };
#pragma unroll
            for (int kk = 0; kk < 8; ++kk)
                acc = __builtin_amdgcn_mfma_f32_16x16x32_bf16(
                    af[kk], wf[nl * 8 + kk], acc, 0, 0, 0);
            const int col = (2 * wv + nl) * 16 + lm;
            if (q == 0) out[(size_t)batch * 128 + col] = acc[0];
        }
    }
}

extern "C" void kernel_launch(void* const* d_in, const int* in_sizes, int n_in,
                              void* d_out, int out_size, void* d_ws, size_t ws_size,
                              hipStream_t stream) {
    const int*   wid = (const int*)d_in[0];      // (256, 2048) int32
    const float* emb = (const float*)d_in[1];    // (100000, 128) fp32
    const float* W   = (const float*)d_in[2];    // (128, 256) fp32
    const float* b   = (const float*)d_in[3];    // (128,) fp32
    float* out = (float*)d_out;                  // (256, 128) fp32

    __bf16* wpack = (__bf16*)d_ws;               // 32768 elems = 64 KB
    __bf16* y     = wpack + 32768;               // (256,32,128) bf16 = 2 MB
    unsigned int* cnt = (unsigned int*)(y + 256 * 32 * 128);  // 256 x u32 = 1 KB

    pack_w_kernel<<<16, 256, 0, stream>>>(W, wpack, cnt);
    tree_kernel<<<4096, 256, 0, stream>>>(wid, emb, wpack, b, y, cnt, out);
}

// Round 3
// 146.272 us; speedup vs baseline: 6.7901x; 4.6631x over previous
//
#include <hip/hip_runtime.h>

// RecursiveNN: 11-level binary tree, shared linear map W(128x256)+b, bf16 MFMA.
// Fused 2-kernel pipeline:
//   pack_w: W -> per-lane MFMA B-fragment order (bf16) + zero per-batch counters.
//   tree:   one block = 128 contiguous leaves; fp32 gather + packed cvt -> LDS;
//           7 fused level-steps (128->2); per-batch atomic election: the 16th
//           (last) group of a batch runs the final 5 levels (32->1) in-block.
// Cross-block coherence WITHOUT __threadfence (round-2 post-mortem: threadfence
// = buffer_wbl2 per wave = L2-writeback storm, +560us): root rows go through
// agent-scope relaxed atomic u32 stores (sc1, write-through to the coherent
// point), drained by s_waitcnt vmcnt(0), then a relaxed agent atomicAdd; the
// winner reads them back with agent-scope relaxed atomic loads (bypass stale
// L1/L2). Only communicated data pays the coherence cost.
// LDS layout: STRIDE=136 padded rows (272 B) -> row rotates banks by 4; measured
// 0 conflicts. 43520 B total -> 3 blocks/CU. launch_bounds(256,3): proven
// no-spill codegen (72 VGPR incl. AGPR-resident wf). (256,4) forces a 128-reg
// budget -> scratch spill, 19x regression (round-1 post-mortem).

typedef __bf16 bf16x8 __attribute__((ext_vector_type(8)));
typedef __bf16 bf16x4 __attribute__((ext_vector_type(4)));
typedef float f32x4 __attribute__((ext_vector_type(4)));

#define STRIDE 136  // 128 cols + 8 pad bf16 = 272B rows; 0 LDS conflicts measured

__device__ __forceinline__ unsigned int pack_bf2(float a, float b) {
    union { __bf16 h; unsigned short s; } ua, ub;
    ua.h = (__bf16)a; ub.h = (__bf16)b;
    return (unsigned int)ua.s | ((unsigned int)ub.s << 16);
}

// Pack W (fp32 128x256) into MFMA B-fragment lane order (bf16):
//   frag f=nl*8+kk, wave wv, lane l: elem j = W[o][d+j],
//   o=(2wv+nl)*16+(l&15), d=kk*32+(l>>4)*8; stored at wpack[(f*256+tid)*8].
// Block 0 also zeroes the 256 per-batch election counters.
__global__ void pack_w_kernel(const float* __restrict__ W,
                              __bf16* __restrict__ wpack,
                              unsigned int* __restrict__ cnt) {
    const int f = blockIdx.x;
    const int tid = threadIdx.x;
    if (f == 0) cnt[tid] = 0u;
    const int wv = tid >> 6, l = tid & 63;
    const int nl = f >> 3, kk = f & 7;
    const int o = ((wv << 1) + nl) * 16 + (l & 15);
    const int d = kk * 32 + ((l >> 4) << 3);
    const float* src = W + o * 256 + d;
    bf16x8 h;
#pragma unroll
    for (int j = 0; j < 8; ++j) h[j] = (__bf16)src[j];
    *(bf16x8*)(wpack + (size_t)(f * 256 + tid) * 8) = h;
}

// One level-step: NOUT local outputs from 2*NOUT local input rows.
// src0 = rows 0..31, src1 = rows 32..63 (unused when NOUT<=16). Ends in barrier.
template <int NOUT>
__device__ __forceinline__ void level_step(
    const __bf16* src0, const __bf16* src1, __bf16* dst,
    const bf16x8* wf, const float* bval, int wv, int q, int lm)
{
    const int ntm = (NOUT + 15) >> 4;
#pragma unroll
    for (int mt = 0; mt < ntm; ++mt) {
        const __bf16* src = mt ? src1 : src0;
        // clamp: padded lanes broadcast row 0/1 (free; no garbage traffic)
        const int me = (NOUT >= 16) ? lm : (lm < NOUT ? lm : 0);
        bf16x8 af[8];
#pragma unroll
        for (int kk = 0; kk < 8; ++kk) {
            const int hi = kk >> 2;                   // k >= 128 half
            const int col = (kk & 3) * 32 + q * 8;
            const int row = 2 * me + hi;              // local row 0..31
            af[kk] = *(const bf16x8*)&src[row * STRIDE + col];
        }
#pragma unroll
        for (int nl = 0; nl < 2; ++nl) {
            f32x4 acc = { bval[nl], bval[nl], bval[nl], bval[nl] };
#pragma unroll
            for (int kk = 0; kk < 8; ++kk)
                acc = __builtin_amdgcn_mfma_f32_16x16x32_bf16(
                    af[kk], wf[nl * 8 + kk], acc, 0, 0, 0);
            const int col = (2 * wv + nl) * 16 + lm;  // D col = lane&15
            const bf16x4 hv = __builtin_convertvector(acc, bf16x4);
#pragma unroll
            for (int r = 0; r < 4; ++r) {
                const int row = mt * 16 + q * 4 + r;  // D row
                if (row < NOUT)
                    dst[row * STRIDE + col] = hv[r];
            }
        }
    }
    __syncthreads();
}

// 4 input rows -> 2 subtree roots, packed (row0|row1<<16) u32, stored to global
// via agent-scope relaxed atomic stores (sc1: visible at coherent point once
// vmcnt retires). No barrier.
__device__ __forceinline__ void level_final(
    const __bf16* src, unsigned int* yrow,
    const bf16x8* wf, const float* bval, int wv, int q, int lm)
{
    const int me = (lm < 2) ? lm : 0;
    bf16x8 af[8];
#pragma unroll
    for (int kk = 0; kk < 8; ++kk) {
        const int hi = kk >> 2;
        const int col = (kk & 3) * 32 + q * 8;
        af[kk] = *(const bf16x8*)&src[(2 * me + hi) * STRIDE + col];
    }
#pragma unroll
    for (int nl = 0; nl < 2; ++nl) {
        f32x4 acc = { bval[nl], bval[nl], bval[nl], bval[nl] };
#pragma unroll
        for (int kk = 0; kk < 8; ++kk)
            acc = __builtin_amdgcn_mfma_f32_16x16x32_bf16(
                af[kk], wf[nl * 8 + kk], acc, 0, 0, 0);
        const int col = (2 * wv + nl) * 16 + lm;
        if (q == 0) {                 // rows 0,1 = quad 0 regs 0,1
            __hip_atomic_store(&yrow[col], pack_bf2(acc[0], acc[1]),
                               __ATOMIC_RELAXED, __HIP_MEMORY_SCOPE_AGENT);
        }
    }
}

// Fused kernel: one block = 128 contiguous leaves of one batch.
// Scratch rotation (abs rows):
//   L1a: A[0:63]  -> B[0:31]    L1b: A[64:127]-> A[0:31]
//   L2:  B+A[0:31]-> A[32:63]   L3:  A[32:63] -> B[0:15]
//   L4:  B[0:15]  -> A[0:7]     L5:  A[0:7]   -> B[0:3]
//   L6:  B[0:3]   -> y32 (128 packed u32, sc1)
// Then: vmcnt(0) drain + per-batch relaxed agent atomicAdd; the block seeing
// old==15 reloads the batch's 32 roots (sc1 loads) and runs the final 5 levels.
__global__ __launch_bounds__(256, 3) void tree_kernel(
    const int* __restrict__ wid, const float* __restrict__ emb,
    const __bf16* __restrict__ wpack, const float* __restrict__ bias,
    unsigned int* __restrict__ y32, unsigned int* __restrict__ cnt,
    float* __restrict__ out)
{
    __shared__ __align__(16) __bf16 bufA[128 * STRIDE];  // 34 KB
    __shared__ __align__(16) __bf16 bufB[32 * STRIDE];   // 8.5 KB -> 43.5 total
    const int tid = threadIdx.x;
    const int batch = blockIdx.x >> 4;   // 16 groups of 128 leaves per batch
    const int grp = blockIdx.x & 15;
    const int wv = tid >> 6, ln = tid & 63, q = ln >> 4, lm = ln & 15;

    // Leaf ids first: they head the gather's dependent chain (wf/bias loads
    // fill the latency shadow).
    const int* wb = wid + batch * 2048 + grp * 128;
    int idreg[16];
#pragma unroll
    for (int i = 0; i < 16; ++i) idreg[i] = wb[(tid >> 5) + 8 * i];

    // W fragments: 16 x (8 bf16) = 64 regs (AGPR-resident), coalesced 256B/thread.
    bf16x8 wf[16];
    const bf16x8* wp = (const bf16x8*)wpack;
#pragma unroll
    for (int f = 0; f < 16; ++f) wf[f] = wp[f * 256 + tid];
    float bval[2];
    bval[0] = bias[(2 * wv + 0) * 16 + lm];
    bval[1] = bias[(2 * wv + 1) * 16 + lm];

    // Gather 128 rows x 128 fp32 -> bf16 LDS (coalesced 512B per row-group).
#pragma unroll
    for (int i = 0; i < 16; ++i) {
        const int row = (tid >> 5) + 8 * i;
        const int c4 = tid & 31;
        const f32x4 v = *(const f32x4*)(emb + (size_t)idreg[i] * 128 + c4 * 4);
        *(bf16x4*)&bufA[row * STRIDE + c4 * 4] =
            __builtin_convertvector(v, bf16x4);
    }
    __syncthreads();

    level_step<32>(bufA,               bufA + 32 * STRIDE, bufB,               wf, bval, wv, q, lm);
    level_step<32>(bufA + 64 * STRIDE, bufA + 96 * STRIDE, bufA,               wf, bval, wv, q, lm);
    level_step<32>(bufB,               bufA,               bufA + 32 * STRIDE, wf, bval, wv, q, lm);
    level_step<16>(bufA + 32 * STRIDE, nullptr,            bufB,               wf, bval, wv, q, lm);
    level_step<8> (bufB,               nullptr,            bufA,               wf, bval, wv, q, lm);
    level_step<4> (bufA,               nullptr,            bufB,               wf, bval, wv, q, lm);
    level_final(bufB, y32 + (size_t)(batch * 16 + grp) * 128,
                wf, bval, wv, q, lm);

    // Drain own sc1 stores to the coherent point, then elect.
    asm volatile("s_waitcnt vmcnt(0)" ::: "memory");
    __syncthreads();          // all threads' roots are agent-visible past here
    int* flagp = (int*)bufB;  // bufB dead after level_final + barrier
    if (tid == 0) {
        const unsigned int old = __hip_atomic_fetch_add(
            &cnt[batch], 1u, __ATOMIC_RELAXED, __HIP_MEMORY_SCOPE_AGENT);
        flagp[0] = (old == 15u);
    }
    __syncthreads();
    if (!flagp[0]) return;

    // ---- winner tail: 32 subtree roots -> 5 levels -> fp32 output row ----
    const unsigned int* yb = y32 + (size_t)batch * 2048;
#pragma unroll
    for (int i = 0; i < 8; ++i) {
        const int flat = tid + 256 * i;       // 2048 packed u32
        const int g = flat >> 7;              // source group
        const int c = flat & 127;             // column
        const unsigned int v = __hip_atomic_load(
            &yb[flat], __ATOMIC_RELAXED, __HIP_MEMORY_SCOPE_AGENT);
        union { unsigned short s; __bf16 h; } lo, hi;
        lo.s = (unsigned short)(v & 0xffffu);
        hi.s = (unsigned short)(v >> 16);
        bufA[(2 * g + 0) * STRIDE + c] = lo.h;
        bufA[(2 * g + 1) * STRIDE + c] = hi.h;
    }
    __syncthreads();
    level_step<16>(bufA, nullptr, bufB, wf, bval, wv, q, lm);
    level_step<8> (bufB, nullptr, bufA, wf, bval, wv, q, lm);
    level_step<4> (bufA, nullptr, bufB, wf, bval, wv, q, lm);
    level_step<2> (bufB, nullptr, bufA, wf, bval, wv, q, lm);

    // 2 rows in bufA -> root (fp32 out).
    {
        bf16x8 af[8];
#pragma unroll
        for (int kk = 0; kk < 8; ++kk) {
            const int hi = kk >> 2;
            const int col = (kk & 3) * 32 + q * 8;
            af[kk] = *(const bf16x8*)&bufA[hi * STRIDE + col];
        }
#pragma unroll
        for (int nl = 0; nl < 2; ++nl) {
            f32x4 acc = { bval[nl], bval[nl], bval[nl], bval[nl] };
#pragma unroll
            for (int kk = 0; kk < 8; ++kk)
                acc = __builtin_amdgcn_mfma_f32_16x16x32_bf16(
                    af[kk], wf[nl * 8 + kk], acc, 0, 0, 0);
            const int col = (2 * wv + nl) * 16 + lm;
            if (q == 0) out[(size_t)batch * 128 + col] = acc[0];
        }
    }
}

extern "C" void kernel_launch(void* const* d_in, const int* in_sizes, int n_in,
                              void* d_out, int out_size, void* d_ws, size_t ws_size,
                              hipStream_t stream) {
    const int*   wid = (const int*)d_in[0];      // (256, 2048) int32
    const float* emb = (const float*)d_in[1];    // (100000, 128) fp32
    const float* W   = (const float*)d_in[2];    // (128, 256) fp32
    const float* b   = (const float*)d_in[3];    // (128,) fp32
    float* out = (float*)d_out;                  // (256, 128) fp32

    __bf16* wpack = (__bf16*)d_ws;               // 32768 elems = 64 KB
    unsigned int* y32 = (unsigned int*)(wpack + 32768);  // 256*16*128 u32 = 2 MB
    unsigned int* cnt = y32 + 256 * 2048;        // 256 x u32 = 1 KB

    pack_w_kernel<<<16, 256, 0, stream>>>(W, wpack, cnt);
    tree_kernel<<<4096, 256, 0, stream>>>(wid, emb, wpack, b, y32, cnt, out);
}

// Round 4
// 128.399 us; speedup vs baseline: 7.7353x; 1.1392x over previous
//
#include <hip/hip_runtime.h>

// RecursiveNN: 11-level binary tree, shared linear map W(128x256)+b, bf16 MFMA.
// Two-kernel structure (fusion reverted: round-3 post-mortem showed late-elected
// winner tails straggle at ~1 block/CU and cost +25us vs separate dispatch).
//   pack_w:  W -> per-lane MFMA B-fragment order (bf16), 64 KB in ws.
//   tree128: one block = 128 contiguous leaves; SPLIT gather (2 x 64 rows) so
//            LDS = 2 x 64-row buffers = 34816 B -> 4 blocks/CU (was 43520/3).
//            Round-3 L3-warm replays proved the kernel is latency-bound, not
//            BW-bound -> occupancy is the lever.
//   tree32:  one block = one batch; final 5 levels (32->1); fp32 output.
// Register budget for 4 blocks/CU: total <= 128/thread. af[8]->af[4] per K-half
// (-16 VGPR), idreg 16->8 per gather phase (-8); wf = 64 AGPR. launch_bounds
// (256,4). Spill tripwire: WRITE_SIZE >> 2 MB means regalloc missed -> revert.
// LDS: STRIDE=136 padded rows (272 B) -> row rotates banks by 4; 0 conflicts
// measured. No unpadded-swizzle experiments (round-1 lesson).

typedef __bf16 bf16x8 __attribute__((ext_vector_type(8)));
typedef __bf16 bf16x4 __attribute__((ext_vector_type(4)));
typedef float f32x4 __attribute__((ext_vector_type(4)));

#define STRIDE 136  // 128 cols + 8 pad bf16 = 272B rows; 0 LDS conflicts measured

// Pack W (fp32 128x256) into MFMA B-fragment lane order (bf16):
//   frag f=nl*8+kk, wave wv, lane l: elem j = W[o][d+j],
//   o=(2wv+nl)*16+(l&15), d=kk*32+(l>>4)*8; stored at wpack[(f*256+tid)*8].
__global__ void pack_w_kernel(const float* __restrict__ W,
                              __bf16* __restrict__ wpack) {
    const int f = blockIdx.x;
    const int tid = threadIdx.x;
    const int wv = tid >> 6, l = tid & 63;
    const int nl = f >> 3, kk = f & 7;
    const int o = ((wv << 1) + nl) * 16 + (l & 15);
    const int d = kk * 32 + ((l >> 4) << 3);
    const float* src = W + o * 256 + d;
    bf16x8 h;
#pragma unroll
    for (int j = 0; j < 8; ++j) h[j] = (__bf16)src[j];
    *(bf16x8*)(wpack + (size_t)(f * 256 + tid) * 8) = h;
}

// One level-step: NOUT local outputs from 2*NOUT local input rows.
// src0 = rows 0..31, src1 = rows 32..63 (unused when NOUT<=16). Ends in barrier.
// K split into two halves (af[4] live at a time, -16 VGPR vs af[8]); per-acc
// K-accumulation order kk=0..7 preserved (bit-identical to round-0 numerics).
template <int NOUT>
__device__ __forceinline__ void level_step(
    const __bf16* src0, const __bf16* src1, __bf16* dst,
    const bf16x8* wf, const float* bval, int wv, int q, int lm)
{
    const int ntm = (NOUT + 15) >> 4;
#pragma unroll
    for (int mt = 0; mt < ntm; ++mt) {
        const __bf16* src = mt ? src1 : src0;
        // clamp: padded lanes broadcast row 0/1 (free; no garbage traffic)
        const int me = (NOUT >= 16) ? lm : (lm < NOUT ? lm : 0);
        f32x4 acc[2];
        acc[0] = f32x4{ bval[0], bval[0], bval[0], bval[0] };
        acc[1] = f32x4{ bval[1], bval[1], bval[1], bval[1] };
#pragma unroll
        for (int kh = 0; kh < 2; ++kh) {        // K half: rows 2me / 2me+1
            const int row = 2 * me + kh;
            bf16x8 af[4];
#pragma unroll
            for (int j = 0; j < 4; ++j)
                af[j] = *(const bf16x8*)&src[row * STRIDE + j * 32 + q * 8];
#pragma unroll
            for (int nl = 0; nl < 2; ++nl)
#pragma unroll
                for (int j = 0; j < 4; ++j)
                    acc[nl] = __builtin_amdgcn_mfma_f32_16x16x32_bf16(
                        af[j], wf[nl * 8 + kh * 4 + j], acc[nl], 0, 0, 0);
        }
#pragma unroll
        for (int nl = 0; nl < 2; ++nl) {
            const int col = (2 * wv + nl) * 16 + lm;  // D col = lane&15
            const bf16x4 hv = __builtin_convertvector(acc[nl], bf16x4);
#pragma unroll
            for (int r = 0; r < 4; ++r) {
                const int row = mt * 16 + q * 4 + r;  // D row
                if (row < NOUT)
                    dst[row * STRIDE + col] = hv[r];
            }
        }
    }
    __syncthreads();
}

// 4 input rows -> 2 subtree roots straight to global (bf16). No barrier.
__device__ __forceinline__ void level_final(
    const __bf16* src, __bf16* yrow,
    const bf16x8* wf, const float* bval, int wv, int q, int lm)
{
    const int me = (lm < 2) ? lm : 0;
    f32x4 acc[2];
    acc[0] = f32x4{ bval[0], bval[0], bval[0], bval[0] };
    acc[1] = f32x4{ bval[1], bval[1], bval[1], bval[1] };
#pragma unroll
    for (int kh = 0; kh < 2; ++kh) {
        const int row = 2 * me + kh;
        bf16x8 af[4];
#pragma unroll
        for (int j = 0; j < 4; ++j)
            af[j] = *(const bf16x8*)&src[row * STRIDE + j * 32 + q * 8];
#pragma unroll
        for (int nl = 0; nl < 2; ++nl)
#pragma unroll
            for (int j = 0; j < 4; ++j)
                acc[nl] = __builtin_amdgcn_mfma_f32_16x16x32_bf16(
                    af[j], wf[nl * 8 + kh * 4 + j], acc[nl], 0, 0, 0);
    }
#pragma unroll
    for (int nl = 0; nl < 2; ++nl) {
        const int col = (2 * wv + nl) * 16 + lm;
        if (q == 0) {                 // rows 0,1 = quad 0 regs 0,1
            yrow[0 * 128 + col] = (__bf16)acc[nl][0];
            yrow[1 * 128 + col] = (__bf16)acc[nl][1];
        }
    }
}

// Gather 64 embedding rows (leaf ids wb64[0..63]) -> dstA rows 0..63 as bf16.
// 8 ids/thread (32 lanes share each id -> broadcast loads); coalesced 512B/row.
__device__ __forceinline__ void gather64(
    const int* wb64, const float* emb, __bf16* dstA, int tid)
{
    int idreg[8];
#pragma unroll
    for (int i = 0; i < 8; ++i) idreg[i] = wb64[(tid >> 5) + 8 * i];
#pragma unroll
    for (int i = 0; i < 8; ++i) {
        const int row = (tid >> 5) + 8 * i;
        const int c4 = tid & 31;
        const f32x4 v = *(const f32x4*)(emb + (size_t)idreg[i] * 128 + c4 * 4);
        *(bf16x4*)&dstA[row * STRIDE + c4 * 4] =
            __builtin_convertvector(v, bf16x4);
    }
}

// Kernel 1: one block = 128 contiguous leaves of one batch, split-gather ladder:
//   gather h1 -> A[0:63]; L1h1: A -> B[0:31]
//   gather h2 -> A[0:63]; L1h2: A -> B[32:63]
//   L2: B[0:63] -> A[0:31]   L3: A[0:31] -> B[0:15]
//   L4: B[0:15] -> A[0:7]    L5: A[0:7]  -> B[0:3]
//   L6: B[0:3]  -> global roots (2 rows)
__global__ __launch_bounds__(256, 4) void tree128_kernel(
    const int* __restrict__ wid, const float* __restrict__ emb,
    const __bf16* __restrict__ wpack, const float* __restrict__ bias,
    __bf16* __restrict__ yout)
{
    __shared__ __align__(16) __bf16 bufA[64 * STRIDE];  // 17408 B
    __shared__ __align__(16) __bf16 bufB[64 * STRIDE];  // 17408 B -> 34816 total
    const int tid = threadIdx.x;
    const int batch = blockIdx.x >> 4;   // 16 groups of 128 leaves per batch
    const int grp = blockIdx.x & 15;
    const int wv = tid >> 6, ln = tid & 63, q = ln >> 4, lm = ln & 15;

    // W fragments: 16 x (8 bf16) = 64 regs (AGPR-resident), coalesced 256B/thread.
    bf16x8 wf[16];
    const bf16x8* wp = (const bf16x8*)wpack;
#pragma unroll
    for (int f = 0; f < 16; ++f) wf[f] = wp[f * 256 + tid];
    float bval[2];
    bval[0] = bias[(2 * wv + 0) * 16 + lm];
    bval[1] = bias[(2 * wv + 1) * 16 + lm];

    const int* wb = wid + batch * 2048 + grp * 128;

    gather64(wb, emb, bufA, tid);
    __syncthreads();
    // leaves 0..63 -> B[0:31]
    level_step<32>(bufA, bufA + 32 * STRIDE, bufB,
                   wf, bval, wv, q, lm);
    gather64(wb + 64, emb, bufA, tid);   // ds_writes ordered after the barrier
    __syncthreads();
    // leaves 64..127 -> B[32:63]
    level_step<32>(bufA, bufA + 32 * STRIDE, bufB + 32 * STRIDE,
                   wf, bval, wv, q, lm);
    level_step<32>(bufB, bufB + 32 * STRIDE, bufA, wf, bval, wv, q, lm);
    level_step<16>(bufA, nullptr,            bufB, wf, bval, wv, q, lm);
    level_step<8> (bufB, nullptr,            bufA, wf, bval, wv, q, lm);
    level_step<4> (bufA, nullptr,            bufB, wf, bval, wv, q, lm);
    level_final(bufB, yout + (size_t)(batch * 32 + grp * 2) * 128,
                wf, bval, wv, q, lm);
}

// Kernel 2: one block = one batch; 32 subtree roots -> 5 levels -> fp32 row.
__global__ __launch_bounds__(256) void tree32_kernel(
    const __bf16* __restrict__ yin, const __bf16* __restrict__ wpack,
    const float* __restrict__ bias, float* __restrict__ out)
{
    __shared__ __align__(16) __bf16 buf0[32 * STRIDE];  // 8704 B
    __shared__ __align__(16) __bf16 buf1[16 * STRIDE];  // 4352 B
    const int tid = threadIdx.x;
    const int batch = blockIdx.x;
    const int wv = tid >> 6, ln = tid & 63, q = ln >> 4, lm = ln & 15;

    bf16x8 wf[16];
    const bf16x8* wp = (const bf16x8*)wpack;
#pragma unroll
    for (int f = 0; f < 16; ++f) wf[f] = wp[f * 256 + tid];
    float bval[2];
    bval[0] = bias[(2 * wv + 0) * 16 + lm];
    bval[1] = bias[(2 * wv + 1) * 16 + lm];

#pragma unroll
    for (int i = 0; i < 2; ++i) {
        const int flat = tid + 256 * i;
        const int row = flat >> 4;
        const int c8 = flat & 15;
        const bf16x8 v =
            *(const bf16x8*)(yin + (size_t)(batch * 32 + row) * 128 + c8 * 8);
        *(bf16x8*)&buf0[row * STRIDE + c8 * 8] = v;
    }
    __syncthreads();

    level_step<16>(buf0, nullptr, buf1, wf, bval, wv, q, lm);  // 32->16
    level_step<8> (buf1, nullptr, buf0, wf, bval, wv, q, lm);  // 16->8
    level_step<4> (buf0, nullptr, buf1, wf, bval, wv, q, lm);  // 8->4
    level_step<2> (buf1, nullptr, buf0, wf, bval, wv, q, lm);  // 4->2

    // Final: rows 0,1 of buf0 -> root row (fp32 out).
    {
        f32x4 acc[2];
        acc[0] = f32x4{ bval[0], bval[0], bval[0], bval[0] };
        acc[1] = f32x4{ bval[1], bval[1], bval[1], bval[1] };
#pragma unroll
        for (int kh = 0; kh < 2; ++kh) {
            bf16x8 af[4];
#pragma unroll
            for (int j = 0; j < 4; ++j)
                af[j] = *(const bf16x8*)&buf0[kh * STRIDE + j * 32 + q * 8];
#pragma unroll
            for (int nl = 0; nl < 2; ++nl)
#pragma unroll
                for (int j = 0; j < 4; ++j)
                    acc[nl] = __builtin_amdgcn_mfma_f32_16x16x32_bf16(
                        af[j], wf[nl * 8 + kh * 4 + j], acc[nl], 0, 0, 0);
        }
#pragma unroll
        for (int nl = 0; nl < 2; ++nl) {
            const int col = (2 * wv + nl) * 16 + lm;
            if (q == 0) out[(size_t)batch * 128 + col] = acc[nl][0];
        }
    }
}

extern "C" void kernel_launch(void* const* d_in, const int* in_sizes, int n_in,
                              void* d_out, int out_size, void* d_ws, size_t ws_size,
                              hipStream_t stream) {
    const int*   wid = (const int*)d_in[0];      // (256, 2048) int32
    const float* emb = (const float*)d_in[1];    // (100000, 128) fp32
    const float* W   = (const float*)d_in[2];    // (128, 256) fp32
    const float* b   = (const float*)d_in[3];    // (128,) fp32
    float* out = (float*)d_out;                  // (256, 128) fp32

    __bf16* wpack = (__bf16*)d_ws;               // 32768 elems = 64 KB
    __bf16* y     = wpack + 32768;               // (256,32,128) bf16 = 2 MB

    pack_w_kernel<<<16, 256, 0, stream>>>(W, wpack);
    tree128_kernel<<<4096, 256, 0, stream>>>(wid, emb, wpack, b, y);
    tree32_kernel<<<256, 256, 0, stream>>>(y, wpack, b, out);
}